// Round 1
// baseline (151.856 us; speedup 1.0000x reference)
//
#include <hip/hip_runtime.h>
#include <stdint.h>

typedef float  float4v  __attribute__((ext_vector_type(4)));
typedef short  short8v  __attribute__((ext_vector_type(8)));
typedef unsigned short ushort4v __attribute__((ext_vector_type(4)));

// Problem constants (N=8192, n_in=256, m=256, k=8)
#define NROWS 8192
#define KDIM  512     // GEMM inner dim = n_in + m
#define GCOLS 8192    // 4*m*k

__device__ __forceinline__ unsigned short f2bf(float f) {
  union { float f; unsigned int u; } v; v.f = f;
  return (unsigned short)((v.u + 0x7FFFu + ((v.u >> 16) & 1u)) >> 16);
}

__device__ __forceinline__ float sigm(float x) {
  float e = __expf(-fabsf(x));
  float s = 1.0f / (1.0f + e);
  return x >= 0.0f ? s : 1.0f - s;
}
__device__ __forceinline__ float tanh_(float x) {
  float e = __expf(-2.0f * fabsf(x));
  float t = (1.0f - e) / (1.0f + e);
  return x >= 0.0f ? t : -t;
}

__device__ __forceinline__ void gll16(const void* g, void* l) {
  __builtin_amdgcn_global_load_lds((const __attribute__((address_space(1))) void*)g,
                                   (__attribute__((address_space(3))) void*)l, 16, 0, 0);
}

// ---------------- P1: build A = [x | h] as bf16, row-major [8192][512] ----------------
__global__ void prep_A(const float* __restrict__ x, const float* __restrict__ h,
                       unsigned short* __restrict__ A) {
  int idx = blockIdx.x * 256 + threadIdx.x;       // 0 .. 8192*64-1
  int n  = idx >> 6;
  int i4 = (idx & 63) << 2;
  float4v xv = *(const float4v*)(x + (size_t)n * 256 + i4);
  float4v hv = *(const float4v*)(h + (size_t)n * 256 + i4);
  ushort4v xa, ha;
#pragma unroll
  for (int j = 0; j < 4; ++j) { xa[j] = f2bf(xv[j]); ha[j] = f2bf(hv[j]); }
  *(ushort4v*)(A + (size_t)n * 512 + i4)       = xa;
  *(ushort4v*)(A + (size_t)n * 512 + 256 + i4) = ha;
}

// ---------------- P2: Bt[c][kk] = W(kk, c), bf16, [8192][512] (K-contiguous) ----------
__global__ void prep_Bt(const float* __restrict__ Wx, const float* __restrict__ Wh,
                        unsigned short* __restrict__ Bt) {
  __shared__ float tile[32][33];
  int c0 = blockIdx.x * 32;
  int k0 = blockIdx.y * 32;
  int tx = threadIdx.x, ty = threadIdx.y;  // 32 x 8
#pragma unroll
  for (int q = 0; q < 4; ++q) {
    int kk = k0 + ty + q * 8;
    float v = (kk < 256) ? Wx[(size_t)kk * 8192 + c0 + tx]
                         : Wh[(size_t)(kk - 256) * 8192 + c0 + tx];
    tile[ty + q * 8][tx] = v;
  }
  __syncthreads();
#pragma unroll
  for (int q = 0; q < 4; ++q) {
    int c = c0 + ty + q * 8;
    Bt[(size_t)c * 512 + k0 + tx] = f2bf(tile[tx][ty + q * 8]);
  }
}

// ---------------- L: logits + softmax(q_z) + gumbel softmax(z), one wave per row ------
__global__ void logits_kernel(const float* __restrict__ x, const float* __restrict__ h,
                              const float* __restrict__ u, const float* __restrict__ Wxz,
                              const float* __restrict__ Whz, const float* __restrict__ bxz,
                              const void* __restrict__ taup,
                              float* __restrict__ z_out, float* __restrict__ qz_out) {
  int lane = threadIdx.x & 63;
  int n = blockIdx.x * 4 + (threadIdx.x >> 6);
  float4v xv = *(const float4v*)(x + (size_t)n * 256 + lane * 4);
  float4v hv = *(const float4v*)(h + (size_t)n * 256 + lane * 4);
  float p[8];
#pragma unroll
  for (int j = 0; j < 8; ++j) p[j] = 0.0f;
#pragma unroll
  for (int ii = 0; ii < 4; ++ii) {
    int i = lane * 4 + ii;
    float xs = xv[ii], hs = hv[ii];
#pragma unroll
    for (int j = 0; j < 8; ++j)
      p[j] += xs * Wxz[i * 8 + j] + hs * Whz[i * 8 + j];
  }
#pragma unroll
  for (int j = 0; j < 8; ++j)
    for (int off = 32; off > 0; off >>= 1) p[j] += __shfl_down(p[j], off, 64);

  if (lane == 0) {
    // tau: robust to int-1 or float-1.0 storage
    int   iv = ((const int*)taup)[0];
    float fv = ((const float*)taup)[0];
    float tau = (iv >= 1 && iv < 100000) ? (float)iv : fv;
    float tinv = 1.0f / tau;

    float logit[8], e[8];
    float mx = -1e30f;
#pragma unroll
    for (int j = 0; j < 8; ++j) { logit[j] = p[j] + bxz[j]; mx = fmaxf(mx, logit[j]); }
    float s = 0.0f;
#pragma unroll
    for (int j = 0; j < 8; ++j) { e[j] = __expf(logit[j] - mx); s += e[j]; }
    float inv = 1.0f / s;
#pragma unroll
    for (int j = 0; j < 8; ++j) qz_out[(size_t)n * 8 + j] = e[j] * inv;

    float t[8];
    float mt = -1e30f;
#pragma unroll
    for (int j = 0; j < 8; ++j) {
      float uu = u[(size_t)n * 8 + j];
      float g = -__logf(-__logf(uu + 1e-10f) + 1e-10f);
      t[j] = (logit[j] + g) * tinv;
      mt = fmaxf(mt, t[j]);
    }
    float s2 = 0.0f;
#pragma unroll
    for (int j = 0; j < 8; ++j) { e[j] = __expf(t[j] - mt); s2 += e[j]; }
    float inv2 = 1.0f / s2;
#pragma unroll
    for (int j = 0; j < 8; ++j) z_out[(size_t)n * 8 + j] = e[j] * inv2;
  }
}

// ---------------- G: fused gates GEMM + LSTM epilogue + k-reduction -------------------
// Tile: 64 rows x 512 gate-cols (4 gates x 8 kk x 16 mm). 8 waves: wr=wid>>2 (rows),
// wc=wid&3 owns kk in {2wc, 2wc+1} for all 4 gates -> LSTM combine is wave-local.
__global__ __launch_bounds__(512, 4) void gates_kernel(
    const unsigned short* __restrict__ A,   // [8192][512] bf16
    const unsigned short* __restrict__ Bt,  // [8192][512] bf16 (col-major of B)
    const float* __restrict__ c0g,          // [8192][256]
    const float* __restrict__ bias,         // [8192]
    const float* __restrict__ zg,           // [8192][8]
    float* __restrict__ h_out, float* __restrict__ c_out) {
  __shared__ char smem[73728];              // A-tile 8KB + Bt-tile 64KB

  int tid  = threadIdx.x;
  int lane = tid & 63;
  int gl   = lane >> 4;
  int ml   = lane & 15;
  int wid  = tid >> 6;
  int wr   = wid >> 2;
  int wc   = wid & 3;
  int rb   = blockIdx.x & 127;
  int cb   = blockIdx.x >> 7;
  int row0 = rb << 6;
  int mm0  = cb << 4;

  const char* Abp = (const char*)A;
  const char* Btp = (const char*)Bt;

  // staging source offsets (bytes), swizzled at 16B-granule level: q' = q ^ (row&7)
  int a_row = tid >> 3;
  int Aoff = ((row0 + a_row) << 10) + ((((tid & 7) ^ (a_row & 7))) << 4);
  int Boff[8];
#pragma unroll
  for (int r = 0; r < 8; ++r) {
    int row_l = (r << 6) + (tid >> 3);
    int group = row_l >> 4;                                   // g*8 + kk
    int col   = ((group >> 3) << 11) + ((group & 7) << 8) + mm0 + (row_l & 15);
    Boff[r] = (col << 10) + ((((tid & 7) ^ (row_l & 7))) << 4);
  }

  float4v acc[2][4][2];
#pragma unroll
  for (int a = 0; a < 2; ++a)
#pragma unroll
    for (int b = 0; b < 4; ++b)
#pragma unroll
      for (int c = 0; c < 2; ++c)
#pragma unroll
        for (int r = 0; r < 4; ++r) acc[a][b][c][r] = 0.0f;

  for (int kt = 0; kt < 8; ++kt) {
    int ko = kt << 7;  // byte offset within a 512-elem (1024B) K row
    gll16(Abp + Aoff + ko, smem + tid * 16);
#pragma unroll
    for (int r = 0; r < 8; ++r)
      gll16(Btp + Boff[r] + ko, smem + 8192 + (r << 13) + tid * 16);
    __syncthreads();

#pragma unroll
    for (int ks = 0; ks < 2; ++ks) {
      int p0 = (ks << 2) + (gl >> 1);
      int o8 = (gl & 1) << 3;
      short8v af[2];
#pragma unroll
      for (int fr = 0; fr < 2; ++fr) {
        int row = (wr << 5) + (fr << 4) + ml;
        const char* rp = smem + row * 128 + o8;
        int rx = row & 7;
        union { short8v v; ushort4v u[2]; } fu;
        fu.u[0] = *(const ushort4v*)(rp + ((p0 ^ rx) << 4));
        fu.u[1] = *(const ushort4v*)(rp + (((p0 + 2) ^ rx) << 4));
        af[fr] = fu.v;
      }
#pragma unroll
      for (int g = 0; g < 4; ++g) {
#pragma unroll
        for (int p = 0; p < 2; ++p) {
          int crow = (((g << 3) + (wc << 1) + p) << 4) + ml;
          const char* rp = smem + 8192 + crow * 128 + o8;
          int rx = crow & 7;
          union { short8v v; ushort4v u[2]; } fu;
          fu.u[0] = *(const ushort4v*)(rp + ((p0 ^ rx) << 4));
          fu.u[1] = *(const ushort4v*)(rp + (((p0 + 2) ^ rx) << 4));
          short8v bfr = fu.v;
#pragma unroll
          for (int fr = 0; fr < 2; ++fr)
            acc[fr][g][p] = __builtin_amdgcn_mfma_f32_16x16x32_bf16(af[fr], bfr, acc[fr][g][p], 0, 0, 0);
        }
      }
    }
    __syncthreads();
  }

  // ------------- epilogue: bias -> activations -> x z -> partial sums over kk --------
  float* ph = (float*)smem;            // [4][64][16]
  float* pc = (float*)(smem + 16384);  // [4][64][16]
  int mm = mm0 + ml;
#pragma unroll
  for (int fr = 0; fr < 2; ++fr) {
#pragma unroll
    for (int r = 0; r < 4; ++r) {
      int rloc = (wr << 5) + (fr << 4) + (gl << 2) + r;
      int n = row0 + rloc;
      float c0v = c0g[(size_t)n * 256 + mm];
      float hsum = 0.0f, csum = 0.0f;
#pragma unroll
      for (int p = 0; p < 2; ++p) {
        int kk = (wc << 1) + p;
        float I = acc[fr][0][p][r] + bias[0 * 2048 + kk * 256 + mm];
        float G = acc[fr][1][p][r] + bias[1 * 2048 + kk * 256 + mm];
        float F = acc[fr][2][p][r] + bias[2 * 2048 + kk * 256 + mm];
        float O = acc[fr][3][p][r] + bias[3 * 2048 + kk * 256 + mm];
        float ct = sigm(F) * c0v + sigm(I) * tanh_(G);
        float ht = sigm(O) * tanh_(ct);
        float zv = zg[(size_t)n * 8 + kk];
        hsum += zv * ht;
        csum += zv * ct;
      }
      ph[((wc << 6) + rloc) * 16 + ml] = hsum;
      pc[((wc << 6) + rloc) * 16 + ml] = csum;
    }
  }
  __syncthreads();
#pragma unroll
  for (int it = 0; it < 2; ++it) {
    int idx = it * 512 + tid;
    int rloc = idx >> 4, mml = idx & 15;
    float hv = 0.0f, cv = 0.0f;
#pragma unroll
    for (int w = 0; w < 4; ++w) {
      hv += ph[((w << 6) + rloc) * 16 + mml];
      cv += pc[((w << 6) + rloc) * 16 + mml];
    }
    int n = row0 + rloc;
    h_out[(size_t)n * 256 + mm0 + mml] = hv;
    c_out[(size_t)n * 256 + mm0 + mml] = cv;
  }
}

extern "C" void kernel_launch(void* const* d_in, const int* in_sizes, int n_in,
                              void* d_out, int out_size, void* d_ws, size_t ws_size,
                              hipStream_t stream) {
  const float* x   = (const float*)d_in[0];
  const float* h0  = (const float*)d_in[1];
  const float* c0  = (const float*)d_in[2];
  const float* u   = (const float*)d_in[3];
  const float* Wxz = (const float*)d_in[4];
  const float* Whz = (const float*)d_in[5];
  const float* Wx4 = (const float*)d_in[6];
  const float* Wh4 = (const float*)d_in[7];
  const float* bxz = (const float*)d_in[8];
  const float* b4  = (const float*)d_in[9];
  const void*  tau = d_in[10];

  float* out    = (float*)d_out;
  float* z_out  = out;                       // [8192][8]
  float* qz_out = out + 65536;               // [8192][8]
  float* h_out  = out + 131072;              // [8192][256]
  float* c_out  = out + 131072 + 2097152;    // [8192][256]

  // workspace: A bf16 (8.39MB) + Bt bf16 (8.39MB) = 16.8MB
  unsigned short* A  = (unsigned short*)d_ws;
  unsigned short* Bt = A + 4194304;

  prep_A<<<2048, 256, 0, stream>>>(x, h0, A);
  prep_Bt<<<dim3(256, 16), dim3(32, 8), 0, stream>>>(Wx4, Wh4, Bt);
  logits_kernel<<<2048, 256, 0, stream>>>(x, h0, u, Wxz, Whz, bxz, tau, z_out, qz_out);
  gates_kernel<<<2048, 512, 0, stream>>>(A, Bt, c0, b4, z_out, h_out, c_out);
}

// Round 2
// 136.977 us; speedup vs baseline: 1.1086x; 1.1086x over previous
//
#include <hip/hip_runtime.h>
#include <stdint.h>

typedef float  float4v  __attribute__((ext_vector_type(4)));
typedef short  short8v  __attribute__((ext_vector_type(8)));
typedef unsigned short ushort4v __attribute__((ext_vector_type(4)));

// Problem constants (N=8192, n_in=256, m=256, k=8)
// GEMM: [8192 x 512] x [512 x 8192] with fused LSTM epilogue.

__device__ __forceinline__ unsigned short f2bf(float f) {
  union { float f; unsigned int u; } v; v.f = f;
  return (unsigned short)((v.u + 0x7FFFu + ((v.u >> 16) & 1u)) >> 16);
}

__device__ __forceinline__ void gll16(const void* g, void* l) {
  __builtin_amdgcn_global_load_lds((const __attribute__((address_space(1))) void*)g,
                                   (__attribute__((address_space(3))) void*)l, 16, 0, 0);
}

#define BARRIER   asm volatile("s_barrier" ::: "memory")
#define WAITLGKM  asm volatile("s_waitcnt lgkmcnt(0)" ::: "memory")
#define WAITVM6   asm volatile("s_waitcnt vmcnt(6)" ::: "memory")
#define WAITVM0   asm volatile("s_waitcnt vmcnt(0)" ::: "memory")
#define PRIO1     __builtin_amdgcn_s_setprio(1)
#define PRIO0     __builtin_amdgcn_s_setprio(0)

// ---------------- P1: A = [x | h] bf16 [8192][512], K-permuted --------------------
// Stored granule (w, si) of 8 elems = orig k {w*32+si*4+0..3} U {w*32+16+si*4+0..3}
__global__ void prep_A(const float* __restrict__ x, const float* __restrict__ h,
                       unsigned short* __restrict__ A) {
  int id = blockIdx.x * 256 + threadIdx.x;       // 8192*64
  int n = id >> 6, gi = id & 63;
  int w = gi >> 2, si = gi & 3;
  const float* src = (w < 8) ? (x + (size_t)n * 256 + w * 32)
                             : (h + (size_t)n * 256 + (w - 8) * 32);
  float4v lo = *(const float4v*)(src + si * 4);
  float4v hi = *(const float4v*)(src + 16 + si * 4);
  ushort4v a, b;
#pragma unroll
  for (int j = 0; j < 4; ++j) { a[j] = f2bf(lo[j]); b[j] = f2bf(hi[j]); }
  unsigned short* dst = A + (size_t)n * 512 + w * 32 + si * 8;
  *(ushort4v*)dst = a;
  *(ushort4v*)(dst + 4) = b;
}

// ---------------- P2: Bt[p][k'] bf16, col-permuted + K-permuted -------------------
// p(C) = (mm>>3)*256 + kk*32 + (mm&7)*4 + g   where C = g*2048 + kk*256 + mm
__global__ void prep_Bt(const float* __restrict__ Wx, const float* __restrict__ Wh,
                        unsigned short* __restrict__ Bt) {
  __shared__ float tile[32][64];
  int tid = threadIdx.x;
  int wi = blockIdx.x & 15;           // k-window (32 k each)
  int C0 = (blockIdx.x >> 4) << 6;    // 64-col group
#pragma unroll
  for (int q = 0; q < 8; ++q) {
    int flat = q * 256 + tid;
    int i = flat >> 6, c = flat & 63;
    int ig = wi * 32 + i;
    float v = (ig < 256) ? Wx[(size_t)ig * 8192 + C0 + c]
                         : Wh[(size_t)(ig - 256) * 8192 + C0 + c];
    tile[i][c] = v;
  }
  __syncthreads();
  int cc = tid & 63, part = tid >> 6;
  int C = C0 + cc;
  int g = C >> 11, kk = (C >> 8) & 7, mm = C & 255;
  int p = ((mm >> 3) << 8) + (kk << 5) + ((mm & 7) << 2) + g;
  ushort4v oa, ob;
#pragma unroll
  for (int e = 0; e < 8; ++e) {
    int il = ((e >> 2) << 4) + (part << 2) + (e & 3);  // orig i within window
    unsigned short bv = f2bf(tile[il][cc]);
    if (e < 4) oa[e] = bv; else ob[e - 4] = bv;
  }
  unsigned short* dst = Bt + (size_t)p * 512 + wi * 32 + part * 8;
  *(ushort4v*)dst = oa;
  *(ushort4v*)(dst + 4) = ob;
}

// ---------------- L: logits + softmax(q_z) + gumbel softmax(z) --------------------
__global__ void logits_kernel(const float* __restrict__ x, const float* __restrict__ h,
                              const float* __restrict__ u, const float* __restrict__ Wxz,
                              const float* __restrict__ Whz, const float* __restrict__ bxz,
                              const void* __restrict__ taup,
                              float* __restrict__ z_out, float* __restrict__ qz_out) {
  int lane = threadIdx.x & 63;
  int n = blockIdx.x * 4 + (threadIdx.x >> 6);
  float4v xv = *(const float4v*)(x + (size_t)n * 256 + lane * 4);
  float4v hv = *(const float4v*)(h + (size_t)n * 256 + lane * 4);
  float p[8];
#pragma unroll
  for (int j = 0; j < 8; ++j) p[j] = 0.0f;
#pragma unroll
  for (int ii = 0; ii < 4; ++ii) {
    int i = lane * 4 + ii;
    float xs = xv[ii], hs = hv[ii];
#pragma unroll
    for (int j = 0; j < 8; ++j)
      p[j] += xs * Wxz[i * 8 + j] + hs * Whz[i * 8 + j];
  }
#pragma unroll
  for (int j = 0; j < 8; ++j)
    for (int off = 32; off > 0; off >>= 1) p[j] += __shfl_down(p[j], off, 64);

  if (lane == 0) {
    int   iv = ((const int*)taup)[0];
    float fv = ((const float*)taup)[0];
    float tau = (iv >= 1 && iv < 100000) ? (float)iv : fv;
    float tinv = 1.0f / tau;

    float logit[8], e[8];
    float mx = -1e30f;
#pragma unroll
    for (int j = 0; j < 8; ++j) { logit[j] = p[j] + bxz[j]; mx = fmaxf(mx, logit[j]); }
    float s = 0.0f;
#pragma unroll
    for (int j = 0; j < 8; ++j) { e[j] = __expf(logit[j] - mx); s += e[j]; }
    float inv = 1.0f / s;
#pragma unroll
    for (int j = 0; j < 8; ++j) qz_out[(size_t)n * 8 + j] = e[j] * inv;

    float t[8];
    float mt = -1e30f;
#pragma unroll
    for (int j = 0; j < 8; ++j) {
      float uu = u[(size_t)n * 8 + j];
      float g = -__logf(-__logf(uu + 1e-10f) + 1e-10f);
      t[j] = (logit[j] + g) * tinv;
      mt = fmaxf(mt, t[j]);
    }
    float s2 = 0.0f;
#pragma unroll
    for (int j = 0; j < 8; ++j) { e[j] = __expf(t[j] - mt); s2 += e[j]; }
    float inv2 = 1.0f / s2;
#pragma unroll
    for (int j = 0; j < 8; ++j) z_out[(size_t)n * 8 + j] = e[j] * inv2;
  }
}

// ---------------- G: 256x256-tile 8-phase GEMM + fused LSTM epilogue --------------
// 8 waves = 2M x 4N. Wave rows: ha*128 + j*32 + wm*16 + ml ; cols: hb*128 + n2*64 + wn*16 + ml
// col decode: kk = hb*4+n2*2+(wn>>1), mml = (wn&1)*4 + (ml>>2), gate = ml&3
__global__ __launch_bounds__(512, 2) void gates_kernel(
    const unsigned short* __restrict__ A,   // [8192][512] bf16 K-permuted
    const unsigned short* __restrict__ Bt,  // [8192][512] bf16 col+K-permuted
    const float* __restrict__ c0g,          // [8192][256]
    const float* __restrict__ bias,         // [8192]
    const float* __restrict__ zg,           // [8192][8]
    float* __restrict__ h_out, float* __restrict__ c_out) {
  __shared__ char smem[131072];  // A: 4 slots x 16KB @0 ; B: 4 slots x 16KB @65536

  const int tid = threadIdx.x;
  const int lane = tid & 63, ml = lane & 15, gl = lane >> 4;
  const int wid = tid >> 6, wm = wid >> 2, wn = wid & 3;

  // XCD-aware bijective swizzle (1024 % 8 == 0)
  int wg = ((blockIdx.x & 7) << 7) + (blockIdx.x >> 3);
  const int rb = wg >> 5, cb = wg & 31;
  const int row0 = rb << 8;

  const char* Abp = (const char*)A + (size_t)rb * 262144;
  const char* Bbp = (const char*)Bt + (size_t)cb * 262144;

  // staging: thread stages LDS slots s=tid and s=tid+512 (16B granules)
  const int srow = tid >> 3, sg = tid & 7;
  const int soff = srow * 1024 + (((sg ^ (srow & 7))) << 4);

  // fragment ds_read byte offsets within a 16KB half-tile [128][64]
  const int aoff0 = ((wm << 4) + ml) * 128 + ((gl ^ (ml & 7)) << 4);
  const int aoff1 = ((wm << 4) + ml) * 128 + (((4 | gl) ^ (ml & 7)) << 4);
  const int boff0 = ((wn << 4) + ml) * 128 + ((gl ^ (ml & 7)) << 4);
  const int boff1 = ((wn << 4) + ml) * 128 + (((4 | gl) ^ (ml & 7)) << 4);

  auto STAGE = [&](int q) {
    int kt_s = q >> 2, pos = q & 3;
    bool isA = (pos == 0) || (pos == 3);
    int half = (pos >= 2) ? 1 : 0;          // order per kt: A0, B0, B1, A1
    int slot = (2 * kt_s + half) & 3;
    const char* src = (isA ? Abp : Bbp) + half * 131072 + kt_s * 128 + soff;
    char* dst = smem + (isA ? 0 : 65536) + slot * 16384 + (tid << 4);
    gll16(src, dst);
    gll16(src + 65536, dst + 8192);
  };

  float4v acc[2][2][4][2];   // [ha][hb][j][n2]
#pragma unroll
  for (int a = 0; a < 2; ++a)
#pragma unroll
    for (int b = 0; b < 2; ++b)
#pragma unroll
      for (int j = 0; j < 4; ++j)
#pragma unroll
        for (int c = 0; c < 2; ++c)
#pragma unroll
          for (int r = 0; r < 4; ++r) acc[a][b][j][c][r] = 0.0f;

  short8v afr[4][2];          // [j][ks]
  short8v bf0[2][2], bf1[2][2];  // [n2][ks]

#define RDA(BASE) { _Pragma("unroll") for (int j = 0; j < 4; ++j) { \
    afr[j][0] = *(const short8v*)(smem + (BASE) + aoff0 + j * 4096); \
    afr[j][1] = *(const short8v*)(smem + (BASE) + aoff1 + j * 4096); } }
#define RDB(BASE, BF) { _Pragma("unroll") for (int n2 = 0; n2 < 2; ++n2) { \
    BF[n2][0] = *(const short8v*)(smem + (BASE) + boff0 + n2 * 8192); \
    BF[n2][1] = *(const short8v*)(smem + (BASE) + boff1 + n2 * 8192); } }
#define MM16(AH, BH, BF) { _Pragma("unroll") for (int j = 0; j < 4; ++j) \
    _Pragma("unroll") for (int n2 = 0; n2 < 2; ++n2) { \
      acc[AH][BH][j][n2] = __builtin_amdgcn_mfma_f32_16x16x32_bf16(afr[j][0], BF[n2][0], acc[AH][BH][j][n2], 0, 0, 0); \
      acc[AH][BH][j][n2] = __builtin_amdgcn_mfma_f32_16x16x32_bf16(afr[j][1], BF[n2][1], acc[AH][BH][j][n2], 0, 0, 0); } }

  // prologue: stage ht q=0..6 (kt0 complete + kt1 A0,B0,B1)
#pragma unroll
  for (int q = 0; q < 7; ++q) STAGE(q);
  WAITVM6;
  BARRIER;

#pragma unroll
  for (int kt = 0; kt < 8; ++kt) {
    const int kb = kt & 1;
    const int Ab0 = kb * 32768, Ab1 = 16384 + kb * 32768;
    const int Bb0 = 65536 + kb * 32768, Bb1 = 65536 + 16384 + kb * 32768;
    const int q0 = 4 * kt + 7;

    // P0: A(half0), B(half0)
    RDA(Ab0); RDB(Bb0, bf0);
    if (q0 <= 31) STAGE(q0);
    BARRIER; WAITLGKM;
    PRIO1; MM16(0, 0, bf0); PRIO0;
    BARRIER;

    // P1: B(half1)
    RDB(Bb1, bf1);
    if (q0 + 1 <= 31) STAGE(q0 + 1);
    BARRIER; WAITLGKM;
    PRIO1; MM16(0, 1, bf1); PRIO0;
    BARRIER;

    // P2: A(half1)
    RDA(Ab1);
    if (q0 + 2 <= 31) STAGE(q0 + 2);
    BARRIER; WAITLGKM;
    PRIO1; MM16(1, 1, bf1); PRIO0;
    BARRIER;

    // P3: no reads (bf0 still in regs)
    if (q0 + 3 <= 31) STAGE(q0 + 3);
    if (kt < 6) { WAITVM6; } else if (kt == 6) { WAITVM0; }
    BARRIER;
    PRIO1; MM16(1, 0, bf0); PRIO0;
    BARRIER;
  }
#undef RDA
#undef RDB
#undef MM16

  // ---------------- fused LSTM epilogue ----------------
  {
    const int grole = ml & 3;       // lane's gate pre-transpose == row offset post
    const int mlo = ml >> 2;
    const int mml = ((wn & 1) << 2) | mlo;
    const int mmg = (cb << 3) + mml;
    float* pbuf = (float*)smem;     // [wn][256][4][2] f32 = 32KB

#pragma unroll
    for (int ha = 0; ha < 2; ++ha) {
#pragma unroll
      for (int j = 0; j < 4; ++j) {
        int rloc = ha * 128 + j * 32 + wm * 16 + gl * 4 + grole;
        int nrow = row0 + rloc;
        float c0v = c0g[(size_t)nrow * 256 + mmg];
        float hsum = 0.f, csum = 0.f;
#pragma unroll
        for (int hb = 0; hb < 2; ++hb) {
#pragma unroll
          for (int n2 = 0; n2 < 2; ++n2) {
            int kk = hb * 4 + n2 * 2 + (wn >> 1);
            float bown = bias[grole * 2048 + kk * 256 + mmg];
            float4v v = acc[ha][hb][j][n2];
            // per-lane activation of own gate (tanh for grole==1, sigmoid else)
            bool isg = (grole == 1);
            float s0, s1, s2, s3;
            {
              float b0 = v[0] + bown, b1 = v[1] + bown, b2 = v[2] + bown, b3 = v[3] + bown;
              float a0 = isg ? b0 + b0 : b0;
              float a1 = isg ? b1 + b1 : b1;
              float a2 = isg ? b2 + b2 : b2;
              float a3 = isg ? b3 + b3 : b3;
              s0 = __builtin_amdgcn_rcpf(1.f + __expf(-a0));
              s1 = __builtin_amdgcn_rcpf(1.f + __expf(-a1));
              s2 = __builtin_amdgcn_rcpf(1.f + __expf(-a2));
              s3 = __builtin_amdgcn_rcpf(1.f + __expf(-a3));
              if (isg) { s0 = fmaf(2.f, s0, -1.f); s1 = fmaf(2.f, s1, -1.f);
                         s2 = fmaf(2.f, s2, -1.f); s3 = fmaf(2.f, s3, -1.f); }
            }
            // 4x4 quad transpose (lanes l&3 x regs)
            float sx0 = __shfl_xor(s0, 1, 64), sx1 = __shfl_xor(s1, 1, 64);
            float sx2 = __shfl_xor(s2, 1, 64), sx3 = __shfl_xor(s3, 1, 64);
            bool L1 = (grole & 1) != 0;
            float z0 = L1 ? sx1 : s0;
            float z1 = L1 ? s1 : sx0;
            float z2 = L1 ? sx3 : s2;
            float z3 = L1 ? s3 : sx2;
            float zx0 = __shfl_xor(z0, 2, 64), zx1 = __shfl_xor(z1, 2, 64);
            float zx2 = __shfl_xor(z2, 2, 64), zx3 = __shfl_xor(z3, 2, 64);
            bool L2 = (grole & 2) != 0;
            float w0 = L2 ? zx2 : z0;   // sig(I)
            float w1 = L2 ? zx3 : z1;   // tanh(G)
            float w2 = L2 ? z2 : zx0;   // sig(F)
            float w3 = L2 ? z3 : zx1;   // sig(O)

            float ct = fmaf(w2, c0v, w0 * w1);
            float e2 = __expf(-2.f * ct);
            float th = fmaf(2.f, __builtin_amdgcn_rcpf(1.f + e2), -1.f);
            float ht = w3 * th;
            float zv = zg[(size_t)nrow * 8 + kk];
            hsum = fmaf(zv, ht, hsum);
            csum = fmaf(zv, ct, csum);
          }
        }
        int pidx = ((wn * 256 + rloc) * 4 + mlo) * 2;
        pbuf[pidx] = hsum;
        pbuf[pidx + 1] = csum;
      }
    }
  }
  __syncthreads();
  // cross-wave kk reduction (wn pairs (0,2) and (1,3)) + global write
  {
    float* pbuf = (float*)smem;
#pragma unroll
    for (int i = 0; i < 8; ++i) {
      int idx = i * 512 + tid;              // [hc][row 256][mml 8]
      int hc = idx >> 11;
      int rr = (idx >> 3) & 255;
      int mloc = idx & 7;
      int wl = mloc >> 2, ml2 = mloc & 3;
      float v = pbuf[((wl * 256 + rr) * 4 + ml2) * 2 + hc]
              + pbuf[(((wl + 2) * 256 + rr) * 4 + ml2) * 2 + hc];
      float* dst = hc ? c_out : h_out;
      dst[(size_t)(row0 + rr) * 256 + (cb << 3) + mloc] = v;
    }
  }
}

extern "C" void kernel_launch(void* const* d_in, const int* in_sizes, int n_in,
                              void* d_out, int out_size, void* d_ws, size_t ws_size,
                              hipStream_t stream) {
  const float* x   = (const float*)d_in[0];
  const float* h0  = (const float*)d_in[1];
  const float* c0  = (const float*)d_in[2];
  const float* u   = (const float*)d_in[3];
  const float* Wxz = (const float*)d_in[4];
  const float* Whz = (const float*)d_in[5];
  const float* Wx4 = (const float*)d_in[6];
  const float* Wh4 = (const float*)d_in[7];
  const float* bxz = (const float*)d_in[8];
  const float* b4  = (const float*)d_in[9];
  const void*  tau = d_in[10];

  float* out    = (float*)d_out;
  float* z_out  = out;                       // [8192][8]
  float* qz_out = out + 65536;               // [8192][8]
  float* h_out  = out + 131072;              // [8192][256]
  float* c_out  = out + 131072 + 2097152;    // [8192][256]

  unsigned short* A  = (unsigned short*)d_ws;       // 8.4MB
  unsigned short* Bt = A + 4194304;                 // 8.4MB

  prep_A<<<2048, 256, 0, stream>>>(x, h0, A);
  prep_Bt<<<2048, 256, 0, stream>>>(Wx4, Wh4, Bt);
  logits_kernel<<<2048, 256, 0, stream>>>(x, h0, u, Wxz, Whz, bxz, tau, z_out, qz_out);
  gates_kernel<<<1024, 512, 0, stream>>>(A, Bt, c0, b4, z_out, h_out, c_out);
}

// Round 3
// 125.712 us; speedup vs baseline: 1.2080x; 1.0896x over previous
//
#include <hip/hip_runtime.h>
#include <stdint.h>

typedef float  float4v  __attribute__((ext_vector_type(4)));
typedef short  short8v  __attribute__((ext_vector_type(8)));
typedef unsigned short ushort4v __attribute__((ext_vector_type(4)));

// Problem constants (N=8192, n_in=256, m=256, k=8)
// GEMM: [8192 x 512] x [512 x 8192] with fused LSTM epilogue.

__device__ __forceinline__ unsigned short f2bf(float f) {
  union { float f; unsigned int u; } v; v.f = f;
  return (unsigned short)((v.u + 0x7FFFu + ((v.u >> 16) & 1u)) >> 16);
}

__device__ __forceinline__ void gll16(const void* g, void* l) {
  __builtin_amdgcn_global_load_lds((const __attribute__((address_space(1))) void*)g,
                                   (__attribute__((address_space(3))) void*)l, 16, 0, 0);
}

#define BARRIER   asm volatile("s_barrier" ::: "memory")
#define WAITLGKM  asm volatile("s_waitcnt lgkmcnt(0)" ::: "memory")
#define WAITVM6   asm volatile("s_waitcnt vmcnt(6)" ::: "memory")
#define WAITVM0   asm volatile("s_waitcnt vmcnt(0)" ::: "memory")
#define PRIO1     __builtin_amdgcn_s_setprio(1)
#define PRIO0     __builtin_amdgcn_s_setprio(0)

// ------------- P1+L fused: A = [x|h] bf16 K-permuted + logits + softmaxes ---------
// 4 waves/block, one row per wave. Lane i holds x[n][4i..4i+3], h[n][4i..4i+3].
__global__ void prep_logits(const float* __restrict__ x, const float* __restrict__ h,
                            const float* __restrict__ u, const float* __restrict__ Wxz,
                            const float* __restrict__ Whz, const float* __restrict__ bxz,
                            const void* __restrict__ taup,
                            unsigned short* __restrict__ A,
                            float* __restrict__ z_out, float* __restrict__ qz_out) {
  int lane = threadIdx.x & 63;
  int n = blockIdx.x * 4 + (threadIdx.x >> 6);
  float4v xv = *(const float4v*)(x + (size_t)n * 256 + lane * 4);
  float4v hv = *(const float4v*)(h + (size_t)n * 256 + lane * 4);

  // ---- bf16 K-permuted A write: granule (w,si): lo4 = k{w*32+si*4..}, hi4 = +16
  {
    ushort4v xa, ha;
#pragma unroll
    for (int j = 0; j < 4; ++j) { xa[j] = f2bf(xv[j]); ha[j] = f2bf(hv[j]); }
    int w = lane >> 3, si = lane & 3, hi = (lane & 4) ? 4 : 0;
    unsigned short* dst = A + (size_t)n * 512 + w * 32 + si * 8 + hi;
    *(ushort4v*)dst = xa;
    *(ushort4v*)(dst + 256) = ha;
  }

  // ---- logits
  float p[8];
#pragma unroll
  for (int j = 0; j < 8; ++j) p[j] = 0.0f;
#pragma unroll
  for (int ii = 0; ii < 4; ++ii) {
    int i = lane * 4 + ii;
    float xs = xv[ii], hs = hv[ii];
#pragma unroll
    for (int j = 0; j < 8; ++j)
      p[j] += xs * Wxz[i * 8 + j] + hs * Whz[i * 8 + j];
  }
#pragma unroll
  for (int j = 0; j < 8; ++j)
    for (int off = 32; off > 0; off >>= 1) p[j] += __shfl_down(p[j], off, 64);

  if (lane == 0) {
    int   iv = ((const int*)taup)[0];
    float fv = ((const float*)taup)[0];
    float tau = (iv >= 1 && iv < 100000) ? (float)iv : fv;
    float tinv = 1.0f / tau;

    float logit[8], e[8];
    float mx = -1e30f;
#pragma unroll
    for (int j = 0; j < 8; ++j) { logit[j] = p[j] + bxz[j]; mx = fmaxf(mx, logit[j]); }
    float s = 0.0f;
#pragma unroll
    for (int j = 0; j < 8; ++j) { e[j] = __expf(logit[j] - mx); s += e[j]; }
    float inv = 1.0f / s;
#pragma unroll
    for (int j = 0; j < 8; ++j) qz_out[(size_t)n * 8 + j] = e[j] * inv;

    float t[8];
    float mt = -1e30f;
#pragma unroll
    for (int j = 0; j < 8; ++j) {
      float uu = u[(size_t)n * 8 + j];
      float g = -__logf(-__logf(uu + 1e-10f) + 1e-10f);
      t[j] = (logit[j] + g) * tinv;
      mt = fmaxf(mt, t[j]);
    }
    float s2 = 0.0f;
#pragma unroll
    for (int j = 0; j < 8; ++j) { e[j] = __expf(t[j] - mt); s2 += e[j]; }
    float inv2 = 1.0f / s2;
#pragma unroll
    for (int j = 0; j < 8; ++j) z_out[(size_t)n * 8 + j] = e[j] * inv2;
  }
}

// ---------------- P2: Bt[p][k'] bf16, col-permuted + K-permuted -------------------
// p(C) = (mm>>3)*256 + kk*32 + (mm&7)*4 + g   where C = g*2048 + kk*256 + mm
__global__ void prep_Bt(const float* __restrict__ Wx, const float* __restrict__ Wh,
                        unsigned short* __restrict__ Bt) {
  __shared__ float tile[32][64];
  int tid = threadIdx.x;
  int wi = blockIdx.x & 15;           // k-window (32 k each)
  int C0 = (blockIdx.x >> 4) << 6;    // 64-col group
#pragma unroll
  for (int q = 0; q < 8; ++q) {
    int flat = q * 256 + tid;
    int i = flat >> 6, c = flat & 63;
    int ig = wi * 32 + i;
    float v = (ig < 256) ? Wx[(size_t)ig * 8192 + C0 + c]
                         : Wh[(size_t)(ig - 256) * 8192 + C0 + c];
    tile[i][c] = v;
  }
  __syncthreads();
  int cc = tid & 63, part = tid >> 6;
  int C = C0 + cc;
  int g = C >> 11, kk = (C >> 8) & 7, mm = C & 255;
  int p = ((mm >> 3) << 8) + (kk << 5) + ((mm & 7) << 2) + g;
  ushort4v oa, ob;
#pragma unroll
  for (int e = 0; e < 8; ++e) {
    int il = ((e >> 2) << 4) + (part << 2) + (e & 3);  // orig i within window
    unsigned short bv = f2bf(tile[il][cc]);
    if (e < 4) oa[e] = bv; else ob[e - 4] = bv;
  }
  unsigned short* dst = Bt + (size_t)p * 512 + wi * 32 + part * 8;
  *(ushort4v*)dst = oa;
  *(ushort4v*)(dst + 4) = ob;
}

// ---------------- G: 256x256-tile 8-phase GEMM + fused LSTM epilogue --------------
// 8 waves = 2M x 4N. Wave rows: ha*128 + j*32 + wm*16 + ml ; cols: hb*128 + n2*64 + wn*16 + ml
// col decode: kk = hb*4+n2*2+(wn>>1), mml = (wn&1)*4 + (ml>>2), gate = ml&3
__global__ __launch_bounds__(512, 2) void gates_kernel(
    const unsigned short* __restrict__ A,   // [8192][512] bf16 K-permuted
    const unsigned short* __restrict__ Bt,  // [8192][512] bf16 col+K-permuted
    const float* __restrict__ c0g,          // [8192][256]
    const float* __restrict__ bias,         // [8192]
    const float* __restrict__ zg,           // [8192][8]
    float* __restrict__ h_out, float* __restrict__ c_out) {
  __shared__ char smem[131072];  // A: 4 slots x 16KB @0 ; B: 4 slots x 16KB @65536

  const int tid = threadIdx.x;
  const int lane = tid & 63, ml = lane & 15, gl = lane >> 4;
  const int wid = tid >> 6, wm = wid >> 2, wn = wid & 3;

  // XCD-stripe grid mapping (HW: block bid runs on XCD bid%8).
  // XCD x owns rb in {4x..4x+3}, walks cb outer / rb inner:
  //   concurrent 32 blocks/XCD = 8 cb x 4 rb -> L2 working set 2MB(B)+1MB(A) < 4MB.
  const int xcd = blockIdx.x & 7;
  const int j_  = blockIdx.x >> 3;
  const int cb  = j_ >> 2;
  const int rb  = (xcd << 2) | (j_ & 3);
  const int row0 = rb << 8;

  const char* Abp = (const char*)A + (size_t)rb * 262144;
  const char* Bbp = (const char*)Bt + (size_t)cb * 262144;

  // staging: thread stages LDS slots s=tid and s=tid+512 (16B granules)
  const int srow = tid >> 3, sg = tid & 7;
  const int soff = srow * 1024 + (((sg ^ (srow & 7))) << 4);

  // fragment ds_read byte offsets within a 16KB half-tile [128][64]
  const int aoff0 = ((wm << 4) + ml) * 128 + ((gl ^ (ml & 7)) << 4);
  const int aoff1 = ((wm << 4) + ml) * 128 + (((4 | gl) ^ (ml & 7)) << 4);
  const int boff0 = ((wn << 4) + ml) * 128 + ((gl ^ (ml & 7)) << 4);
  const int boff1 = ((wn << 4) + ml) * 128 + (((4 | gl) ^ (ml & 7)) << 4);

  auto STAGE = [&](int q) {
    int kt_s = q >> 2, pos = q & 3;
    bool isA = (pos == 0) || (pos == 3);
    int half = (pos >= 2) ? 1 : 0;          // order per kt: A0, B0, B1, A1
    int slot = (2 * kt_s + half) & 3;
    const char* src = (isA ? Abp : Bbp) + half * 131072 + kt_s * 128 + soff;
    char* dst = smem + (isA ? 0 : 65536) + slot * 16384 + (tid << 4);
    gll16(src, dst);
    gll16(src + 65536, dst + 8192);
  };

  float4v acc[2][2][4][2];   // [ha][hb][j][n2]
#pragma unroll
  for (int a = 0; a < 2; ++a)
#pragma unroll
    for (int b = 0; b < 2; ++b)
#pragma unroll
      for (int j = 0; j < 4; ++j)
#pragma unroll
        for (int c = 0; c < 2; ++c)
#pragma unroll
          for (int r = 0; r < 4; ++r) acc[a][b][j][c][r] = 0.0f;

  short8v afr[4][2];          // [j][ks]
  short8v bf0[2][2], bf1[2][2];  // [n2][ks]

#define RDA(BASE) { _Pragma("unroll") for (int j = 0; j < 4; ++j) { \
    afr[j][0] = *(const short8v*)(smem + (BASE) + aoff0 + j * 4096); \
    afr[j][1] = *(const short8v*)(smem + (BASE) + aoff1 + j * 4096); } }
#define RDB(BASE, BF) { _Pragma("unroll") for (int n2 = 0; n2 < 2; ++n2) { \
    BF[n2][0] = *(const short8v*)(smem + (BASE) + boff0 + n2 * 8192); \
    BF[n2][1] = *(const short8v*)(smem + (BASE) + boff1 + n2 * 8192); } }
#define MM16(AH, BH, BF) { _Pragma("unroll") for (int j = 0; j < 4; ++j) \
    _Pragma("unroll") for (int n2 = 0; n2 < 2; ++n2) { \
      acc[AH][BH][j][n2] = __builtin_amdgcn_mfma_f32_16x16x32_bf16(afr[j][0], BF[n2][0], acc[AH][BH][j][n2], 0, 0, 0); \
      acc[AH][BH][j][n2] = __builtin_amdgcn_mfma_f32_16x16x32_bf16(afr[j][1], BF[n2][1], acc[AH][BH][j][n2], 0, 0, 0); } }

  // prologue: stage q=0..6 (kt0 complete + kt1 A0,B0,B1)
#pragma unroll
  for (int q = 0; q < 7; ++q) STAGE(q);
  WAITVM6;
  BARRIER;

#pragma unroll
  for (int kt = 0; kt < 8; ++kt) {
    const int kb = kt & 1;
    const int Ab0 = kb * 32768, Ab1 = 16384 + kb * 32768;
    const int Bb0 = 65536 + kb * 32768, Bb1 = 65536 + 16384 + kb * 32768;
    const int q0 = 4 * kt + 7;

    // P0: A(half0), B(half0)
    RDA(Ab0); RDB(Bb0, bf0);
    if (q0 <= 31) STAGE(q0);
    BARRIER; WAITLGKM;
    PRIO1; MM16(0, 0, bf0); PRIO0;
    BARRIER;

    // P1: B(half1)
    RDB(Bb1, bf1);
    if (q0 + 1 <= 31) STAGE(q0 + 1);
    BARRIER; WAITLGKM;
    PRIO1; MM16(0, 1, bf1); PRIO0;
    BARRIER;

    // P2: A(half1)
    RDA(Ab1);
    if (q0 + 2 <= 31) STAGE(q0 + 2);
    BARRIER; WAITLGKM;
    PRIO1; MM16(1, 1, bf1); PRIO0;
    BARRIER;

    // P3: no reads (bf0 still in regs)
    if (q0 + 3 <= 31) STAGE(q0 + 3);
    if (kt < 6) { WAITVM6; } else if (kt == 6) { WAITVM0; }
    BARRIER;
    PRIO1; MM16(1, 0, bf0); PRIO0;
    BARRIER;
  }
#undef RDA
#undef RDB
#undef MM16

  // ---------------- fused LSTM epilogue ----------------
  {
    const int grole = ml & 3;       // lane's gate pre-transpose == row offset post
    const int mlo = ml >> 2;
    const int mml = ((wn & 1) << 2) | mlo;
    const int mmg = (cb << 3) + mml;
    float* pbuf = (float*)smem;     // [wn][256][4][2] f32 = 32KB

#pragma unroll
    for (int ha = 0; ha < 2; ++ha) {
#pragma unroll
      for (int j = 0; j < 4; ++j) {
        int rloc = ha * 128 + j * 32 + wm * 16 + gl * 4 + grole;
        int nrow = row0 + rloc;
        float c0v = c0g[(size_t)nrow * 256 + mmg];
        float hsum = 0.f, csum = 0.f;
#pragma unroll
        for (int hb = 0; hb < 2; ++hb) {
#pragma unroll
          for (int n2 = 0; n2 < 2; ++n2) {
            int kk = hb * 4 + n2 * 2 + (wn >> 1);
            float bown = bias[grole * 2048 + kk * 256 + mmg];
            float4v v = acc[ha][hb][j][n2];
            bool isg = (grole == 1);
            float s0, s1, s2, s3;
            {
              float b0 = v[0] + bown, b1 = v[1] + bown, b2 = v[2] + bown, b3 = v[3] + bown;
              float a0 = isg ? b0 + b0 : b0;
              float a1 = isg ? b1 + b1 : b1;
              float a2 = isg ? b2 + b2 : b2;
              float a3 = isg ? b3 + b3 : b3;
              s0 = __builtin_amdgcn_rcpf(1.f + __expf(-a0));
              s1 = __builtin_amdgcn_rcpf(1.f + __expf(-a1));
              s2 = __builtin_amdgcn_rcpf(1.f + __expf(-a2));
              s3 = __builtin_amdgcn_rcpf(1.f + __expf(-a3));
              if (isg) { s0 = fmaf(2.f, s0, -1.f); s1 = fmaf(2.f, s1, -1.f);
                         s2 = fmaf(2.f, s2, -1.f); s3 = fmaf(2.f, s3, -1.f); }
            }
            // 4x4 quad transpose (lanes l&3 x regs)
            float sx0 = __shfl_xor(s0, 1, 64), sx1 = __shfl_xor(s1, 1, 64);
            float sx2 = __shfl_xor(s2, 1, 64), sx3 = __shfl_xor(s3, 1, 64);
            bool L1 = (grole & 1) != 0;
            float z0 = L1 ? sx1 : s0;
            float z1 = L1 ? s1 : sx0;
            float z2 = L1 ? sx3 : s2;
            float z3 = L1 ? s3 : sx2;
            float zx0 = __shfl_xor(z0, 2, 64), zx1 = __shfl_xor(z1, 2, 64);
            float zx2 = __shfl_xor(z2, 2, 64), zx3 = __shfl_xor(z3, 2, 64);
            bool L2 = (grole & 2) != 0;
            float w0 = L2 ? zx2 : z0;   // sig(I)
            float w1 = L2 ? zx3 : z1;   // tanh(G)
            float w2 = L2 ? z2 : zx0;   // sig(F)
            float w3 = L2 ? z3 : zx1;   // sig(O)

            float ct = fmaf(w2, c0v, w0 * w1);
            float e2 = __expf(-2.f * ct);
            float th = fmaf(2.f, __builtin_amdgcn_rcpf(1.f + e2), -1.f);
            float ht = w3 * th;
            float zv = zg[(size_t)nrow * 8 + kk];
            hsum = fmaf(zv, ht, hsum);
            csum = fmaf(zv, ct, csum);
          }
        }
        int pidx = ((wn * 256 + rloc) * 4 + mlo) * 2;
        pbuf[pidx] = hsum;
        pbuf[pidx + 1] = csum;
      }
    }
  }
  __syncthreads();
  // cross-wave kk reduction (wn pairs (0,2) and (1,3)) + global write
  {
    float* pbuf = (float*)smem;
#pragma unroll
    for (int i = 0; i < 8; ++i) {
      int idx = i * 512 + tid;              // [hc][row 256][mml 8]
      int hc = idx >> 11;
      int rr = (idx >> 3) & 255;
      int mloc = idx & 7;
      int wl = mloc >> 2, ml2 = mloc & 3;
      float v = pbuf[((wl * 256 + rr) * 4 + ml2) * 2 + hc]
              + pbuf[(((wl + 2) * 256 + rr) * 4 + ml2) * 2 + hc];
      float* dst = hc ? c_out : h_out;
      dst[(size_t)(row0 + rr) * 256 + (cb << 3) + mloc] = v;
    }
  }
}

extern "C" void kernel_launch(void* const* d_in, const int* in_sizes, int n_in,
                              void* d_out, int out_size, void* d_ws, size_t ws_size,
                              hipStream_t stream) {
  const float* x   = (const float*)d_in[0];
  const float* h0  = (const float*)d_in[1];
  const float* c0  = (const float*)d_in[2];
  const float* u   = (const float*)d_in[3];
  const float* Wxz = (const float*)d_in[4];
  const float* Whz = (const float*)d_in[5];
  const float* Wx4 = (const float*)d_in[6];
  const float* Wh4 = (const float*)d_in[7];
  const float* bxz = (const float*)d_in[8];
  const float* b4  = (const float*)d_in[9];
  const void*  tau = d_in[10];

  float* out    = (float*)d_out;
  float* z_out  = out;                       // [8192][8]
  float* qz_out = out + 65536;               // [8192][8]
  float* h_out  = out + 131072;              // [8192][256]
  float* c_out  = out + 131072 + 2097152;    // [8192][256]

  unsigned short* A  = (unsigned short*)d_ws;       // 8.4MB
  unsigned short* Bt = A + 4194304;                 // 8.4MB

  prep_logits<<<2048, 256, 0, stream>>>(x, h0, u, Wxz, Whz, bxz, tau, A, z_out, qz_out);
  prep_Bt<<<2048, 256, 0, stream>>>(Wx4, Wh4, Bt);
  gates_kernel<<<1024, 512, 0, stream>>>(A, Bt, c0, b4, z_out, h_out, c_out);
}